// Round 8
// baseline (5619.794 us; speedup 1.0000x reference)
//
#include <hip/hip_runtime.h>
#include <math.h>

#define NROWS 8192
#define DIM   64
#define KSEL  32
#define NQ    (NROWS - KSEL)   /* 8160 query rows */
#define P1LEN 512              /* pass-1 exact prefix */
#define CAP   1024             /* per-query candidate list capacity */
#define FILT_CB 256            /* candidates per filter block */
#define PAIRCAP 6291456u       /* 6M survivor pairs (expected ~1.6M) */

typedef __attribute__((ext_vector_type(8))) short bf16x8;
typedef __attribute__((ext_vector_type(4))) float f32x4;

// ---------------------------------------------------------------------------
// Kernel A: row norms replicating XLA:CPU (LLVM-vectorized fused reduce):
//   VF=8 lanes, init 0, per-lane FMA chain, horizontal shuffle-tree
//   ((r0+r4)+(r2+r6)) + ((r1+r5)+(r3+r7)).   [validated bit-exact R8-R13]
// ---------------------------------------------------------------------------
__global__ void norms_kernel(const float* __restrict__ x, float* __restrict__ sq) {
    int j = blockIdx.x * blockDim.x + threadIdx.x;
    if (j >= NROWS) return;
    const float* xr = x + (size_t)j * DIM;
    float r[8];
#pragma unroll
    for (int u = 0; u < 8; ++u) r[u] = 0.0f;
#pragma unroll
    for (int i = 0; i < DIM; i += 8) {
#pragma unroll
        for (int u = 0; u < 8; ++u)
            r[u] = __fmaf_rn(xr[i + u], xr[i + u], r[u]);
    }
    const float s04 = __fadd_rn(r[0], r[4]);
    const float s26 = __fadd_rn(r[2], r[6]);
    const float s15 = __fadd_rn(r[1], r[5]);
    const float s37 = __fadd_rn(r[3], r[7]);
    sq[j] = __fadd_rn(__fadd_rn(s04, s26), __fadd_rn(s15, s37));
}

// ---------------------------------------------------------------------------
// Convert x -> bf16 (RNE), 4 elems/thread.  Also zeroes the pair counter.
// bf16 RNE rel-err <= 2^-8 per element -> rigorous filter margin (below).
// ---------------------------------------------------------------------------
__global__ __launch_bounds__(256)
void convert_kernel(const float* __restrict__ x, unsigned short* __restrict__ xb,
                    unsigned int* __restrict__ paircnt) {
    const int i = (blockIdx.x * blockDim.x + threadIdx.x) * 4;
    if (i == 0) *paircnt = 0u;
    if (i >= NROWS * DIM) return;
    const float4 v = *reinterpret_cast<const float4*>(x + i);
    const float vv[4] = {v.x, v.y, v.z, v.w};
    unsigned short o[4];
#pragma unroll
    for (int u = 0; u < 4; ++u) {
        const unsigned b = __float_as_uint(vv[u]);
        o[u] = (unsigned short)((b + 0x7FFFu + ((b >> 16) & 1u)) >> 16);
    }
    *reinterpret_cast<ushort4*>(xb + i) = make_ushort4(o[0], o[1], o[2], o[3]);
}

// ---------------------------------------------------------------------------
// Pass 1: ONE WAVE per query.  Exact top-32 over prefix [0, min(512, r)):
// 8 keys/lane in registers, 32 shuffle-only extract-min iterations.
// Writes the 32 keys to lists[qi][0..31], cnt[qi]=32, tau0[qi]=32nd key.
// Distance = bit-exact seq-FMA chain k=0..63 (validated).
// ---------------------------------------------------------------------------
__global__ __launch_bounds__(64)
void pass1_kernel(const float* __restrict__ x, const float* __restrict__ sq,
                  unsigned long long* __restrict__ tau0,
                  unsigned int* __restrict__ cnt,
                  unsigned long long* __restrict__ lists) {
    const int qi   = blockIdx.x;        // 0..8159
    const int r    = qi + KSEL;         // query row (wave-uniform)
    const int lane = threadIdx.x;
    const int P    = min(r, P1LEN);

    const float* qp  = x + (size_t)r * DIM;   // uniform -> scalar loads
    const float  sqr = sq[r];

    unsigned long long key[8];
#pragma unroll
    for (int s = 0; s < 8; ++s) {
        const int j = lane + (s << 6);
        unsigned long long k = ~0ull;
        if (j < P) {
            const float4* c4 = reinterpret_cast<const float4*>(x + (size_t)j * DIM);
            float acc = 0.0f;
#pragma unroll
            for (int i = 0; i < DIM / 4; ++i) {
                float4 v = c4[i];
                acc = __fmaf_rn(qp[4 * i + 0], v.x, acc);
                acc = __fmaf_rn(qp[4 * i + 1], v.y, acc);
                acc = __fmaf_rn(qp[4 * i + 2], v.z, acc);
                acc = __fmaf_rn(qp[4 * i + 3], v.w, acc);
            }
            const float dd =
                fmaxf(__fsub_rn(__fadd_rn(sqr, sq[j]), __fmul_rn(2.0f, acc)), 0.0f);
            k = ((unsigned long long)__float_as_uint(dd) << 32) | (unsigned)j;
        }
        key[s] = k;
    }

    unsigned long long pmin = ~0ull;
#pragma unroll
    for (int s = 0; s < 8; ++s) pmin = key[s] < pmin ? key[s] : pmin;

    unsigned long long g = ~0ull;
    for (int it = 0; it < KSEL; ++it) {
        unsigned long long v = pmin;
#pragma unroll
        for (int off = 32; off > 0; off >>= 1) {
            const unsigned long long o = __shfl_down(v, off, 64);
            v = o < v ? o : v;
        }
        g = __shfl(v, 0, 64);
        if (lane == 0) lists[(size_t)qi * CAP + it] = g;
        if (pmin == g) {            // unique winner (keys embed unique j)
#pragma unroll
            for (int s = 0; s < 8; ++s) if (key[s] == g) key[s] = ~0ull;
            pmin = ~0ull;
#pragma unroll
            for (int s = 0; s < 8; ++s) pmin = key[s] < pmin ? key[s] : pmin;
        }
    }
    if (lane == 0) { tau0[qi] = g; cnt[qi] = KSEL; }
}

// ---------------------------------------------------------------------------
// Filter (v7): bf16 MFMA approximate-distance screen over [512, r).
// POST-MORTEM LADDER: every fp32 SIMT pass2 (4x4=165us, 8x8=304/277/243us,
// 4x8=202us, reg-Q=257us) plateaued ~7x above the 24us FMA floor
// (latency/allocator-bound).  v7 moves the screen to matrix cores:
//   * A = 16 query rows (bf16), B = 16 cand cols, mfma_f32_16x16x32_bf16 x2
//     (K=64).  Fragments: A lane l -> row l&15, k=(l>>4)*8..+7 (contig 16B);
//     B lane l -> col l&15, same k chunk; D lane l -> col l&15,
//     row (l>>4)*4+i  [guide §3, m89-verified C/D].
//   * Accept pair iff d_approx <= tau + M,  M = 2^-6*(sqr+sqc): RIGOROUS
//     superset (bf16 RNE err 2^-8/input => dist err <= 2^-7*(sqr+sqc) via
//     Cauchy-Schwarz; 2x slack).  Survivors ~200/query ~ 1.6M pairs.
//   * Wave-aggregated append (ballot + 1 atomic/wave) to a global worklist.
// Exact distances are NOT computed here -- refine_kernel recomputes the
// validated bit-exact fp32 chain for every survivor, so the final lists
// are identical to the old pass2's.  Block = 256 thr = 4 waves x 16 q.
// ---------------------------------------------------------------------------
__global__ __launch_bounds__(256)
void filter_kernel(const unsigned short* __restrict__ xb,
                   const float* __restrict__ sq,
                   const unsigned long long* __restrict__ tau0,
                   unsigned int* __restrict__ paircnt,
                   unsigned int* __restrict__ pairs) {
    const int qb   = blockIdx.x;                        // 64-query tile
    const int jb   = P1LEN + blockIdx.y * FILT_CB;      // candidate tile base
    const int r_hi = min(KSEL + (qb + 1) * 64, NROWS);  // exclusive query cap
    if (jb >= r_hi) return;                             // uniform exit

    const int wave = threadIdx.x >> 6;                  // 0..3
    const int lane = threadIdx.x & 63;
    const int rb   = KSEL + qb * 64 + wave * 16;        // wave's first q row
    const int col  = lane & 15;
    const int kg   = lane >> 4;                         // k-group 0..3

    // A fragments (row rb+col, k = kg*8 + {0..7} and +32): contiguous 16B
    const int arow = min(rb + col, NROWS - 1);
    const bf16x8 a0 = *reinterpret_cast<const bf16x8*>(xb + (size_t)arow * DIM + kg * 8);
    const bf16x8 a1 = *reinterpret_cast<const bf16x8*>(xb + (size_t)arow * DIM + 32 + kg * 8);

    // Epilogue per-lane row data: D rows rb + kg*4 + i
    float sqr[4], thm[4]; int rr[4];
#pragma unroll
    for (int i = 0; i < 4; ++i) {
        const int r = rb + kg * 4 + i;
        rr[i]  = r;
        const int rc = min(r, NROWS - 1);
        sqr[i] = sq[rc];
        thm[i] = (r < NROWS) ? __uint_as_float((unsigned)(tau0[r - KSEL] >> 32))
                             : -1.0f;                   // reject all
    }

    for (int sub = 0; sub < FILT_CB / 16; ++sub) {
        const int j0 = jb + sub * 16;
        if (j0 >= r_hi) break;                          // wave-uniform
        const int j  = j0 + col;
        const int jc = min(j, NROWS - 1);
        const bf16x8 b0 = *reinterpret_cast<const bf16x8*>(xb + (size_t)jc * DIM + kg * 8);
        const bf16x8 b1 = *reinterpret_cast<const bf16x8*>(xb + (size_t)jc * DIM + 32 + kg * 8);
        f32x4 acc = {0.f, 0.f, 0.f, 0.f};
        acc = __builtin_amdgcn_mfma_f32_16x16x32_bf16(a0, b0, acc, 0, 0, 0);
        acc = __builtin_amdgcn_mfma_f32_16x16x32_bf16(a1, b1, acc, 0, 0, 0);
        const float sqc = sq[jc];
#pragma unroll
        for (int i = 0; i < 4; ++i) {
            const float s = __fadd_rn(sqr[i], sqc);
            const float d = __fmaf_rn(-2.0f, acc[i], s);
            const bool accept = (j < rr[i]) && (rr[i] < NROWS) &&
                                (d <= __fmaf_rn(0.015625f, s, thm[i]));
            const unsigned long long mask = __ballot(accept);
            if (mask) {
                const int leader = __builtin_ctzll(mask);
                unsigned base = 0;
                if (lane == leader)
                    base = atomicAdd(paircnt, (unsigned)__popcll(mask));
                base = __shfl(base, leader, 64);
                const unsigned off =
                    base + (unsigned)__popcll(mask & ((1ull << lane) - 1ull));
                if (accept && off < PAIRCAP)
                    pairs[off] = ((unsigned)(rr[i] - KSEL) << 13) | (unsigned)j;
            }
        }
    }
}

// ---------------------------------------------------------------------------
// Refine: one survivor pair per thread (grid-stride).  Recomputes the exact
// VALIDATED bit-exact fp32 chain (k=0..63 ascending, float4 x/y/z/w order)
// and applies the original filter bits <= tau_hi; appends via atomicAdd.
// Final lists == old pass2 output exactly.
// ---------------------------------------------------------------------------
__global__ __launch_bounds__(256)
void refine_kernel(const float* __restrict__ x, const float* __restrict__ sq,
                   const unsigned long long* __restrict__ tau0,
                   const unsigned int* __restrict__ paircnt,
                   const unsigned int* __restrict__ pairs,
                   unsigned int* __restrict__ cnt,
                   unsigned long long* __restrict__ lists) {
    const unsigned np = min(*paircnt, PAIRCAP);
    const unsigned stride = gridDim.x * blockDim.x;
    for (unsigned i = blockIdx.x * blockDim.x + threadIdx.x; i < np; i += stride) {
        const unsigned p = pairs[i];
        const int qi = (int)(p >> 13);
        const int j  = (int)(p & 0x1FFFu);
        const int r  = qi + KSEL;
        const float* qp = x + (size_t)r * DIM;
        const float* cp = x + (size_t)j * DIM;
        float acc = 0.0f;
#pragma unroll
        for (int k = 0; k < DIM; k += 4) {
            const float4 qv = *reinterpret_cast<const float4*>(qp + k);
            const float4 cv = *reinterpret_cast<const float4*>(cp + k);
            acc = __fmaf_rn(qv.x, cv.x, acc);
            acc = __fmaf_rn(qv.y, cv.y, acc);
            acc = __fmaf_rn(qv.z, cv.z, acc);
            acc = __fmaf_rn(qv.w, cv.w, acc);
        }
        const float dd = fmaxf(
            __fsub_rn(__fadd_rn(sq[r], sq[j]), __fmul_rn(2.0f, acc)), 0.0f);
        const unsigned bits = __float_as_uint(dd);
        const unsigned th   = (unsigned)(tau0[qi] >> 32);
        if (bits <= th) {
            const unsigned s = atomicAdd(&cnt[qi], 1u);
            if (s < CAP)
                lists[(size_t)qi * CAP + s] =
                    ((unsigned long long)bits << 32) | (unsigned)j;
        }
    }
}

// ---------------------------------------------------------------------------
// Merge: ONE WAVE per query.  16 keys/lane in registers, 32 shuffle-only
// extract-min iterations.  u64-min = ascending (dist, index), low-index
// ties (validated top_k semantics).  List is a superset of the true top-32.
// ---------------------------------------------------------------------------
__global__ __launch_bounds__(64)
void merge_kernel(const unsigned long long* __restrict__ lists,
                  const unsigned int* __restrict__ cnt,
                  float* __restrict__ out_d, float* __restrict__ out_i) {
    const int qi   = blockIdx.x;     // 0..8159
    const int lane = threadIdx.x;
    const int ne   = min((int)cnt[qi], CAP);
    const unsigned long long* src = lists + (size_t)qi * CAP;

    unsigned long long k[16];
#pragma unroll
    for (int s = 0; s < 16; ++s) {
        const int idx = lane + (s << 6);
        k[s] = (idx < ne) ? src[idx] : ~0ull;
    }
    unsigned long long pmin = ~0ull;
#pragma unroll
    for (int s = 0; s < 16; ++s) pmin = k[s] < pmin ? k[s] : pmin;

    for (int it = 0; it < KSEL; ++it) {
        unsigned long long v = pmin;
#pragma unroll
        for (int off = 32; off > 0; off >>= 1) {
            const unsigned long long o = __shfl_down(v, off, 64);
            v = o < v ? o : v;
        }
        const unsigned long long g = __shfl(v, 0, 64);
        if (lane == 0) {
            out_d[(size_t)qi * KSEL + it] = __uint_as_float((unsigned)(g >> 32));
            out_i[(size_t)qi * KSEL + it] = (float)(unsigned)(g & 0xFFFFFFFFu);
        }
        if (pmin == g) {            // unique winner rescans its registers
#pragma unroll
            for (int s = 0; s < 16; ++s) if (k[s] == g) k[s] = ~0ull;
            pmin = ~0ull;
#pragma unroll
            for (int s = 0; s < 16; ++s) pmin = k[s] < pmin ? k[s] : pmin;
        }
    }
}

extern "C" void kernel_launch(void* const* d_in, const int* in_sizes, int n_in,
                              void* d_out, int out_size, void* d_ws, size_t ws_size,
                              hipStream_t stream) {
    const float* x = (const float*)d_in[0];    // anchor_x [8192, 64] fp32
    float* sq = (float*)d_ws;                                        // 32 KB
    unsigned long long* tau0 =
        (unsigned long long*)((char*)d_ws + 32768);                  // 64 KB
    unsigned int* cnt = (unsigned int*)((char*)d_ws + 98304);        // 32 KB
    unsigned long long* lists =
        (unsigned long long*)((char*)d_ws + 131072);                 // 66.8 MB
    unsigned short* xb =
        (unsigned short*)((char*)d_ws + 66977792);                   // 1 MB bf16
    unsigned int* paircnt =
        (unsigned int*)((char*)d_ws + 68026368);                     // 4 B
    unsigned int* pairs =
        (unsigned int*)((char*)d_ws + 68026624);                     // 24 MB
    float* out_d = (float*)d_out;              // [8160, 32] distances
    float* out_i = out_d + (size_t)NQ * KSEL;  // [8160, 32] indices (as fp32)

    norms_kernel<<<NROWS / 256, 256, 0, stream>>>(x, sq);
    pass1_kernel<<<NQ, 64, 0, stream>>>(x, sq, tau0, cnt, lists);
    convert_kernel<<<NROWS * DIM / 1024, 256, 0, stream>>>(x, xb, paircnt);
    dim3 gf(128, (NROWS - P1LEN) / FILT_CB);   // (query tile, candidate tile)
    filter_kernel<<<gf, 256, 0, stream>>>(xb, sq, tau0, paircnt, pairs);
    refine_kernel<<<2048, 256, 0, stream>>>(x, sq, tau0, paircnt, pairs, cnt, lists);
    merge_kernel<<<NQ, 64, 0, stream>>>(lists, cnt, out_d, out_i);
}

// Round 9
// 430.525 us; speedup vs baseline: 13.0534x; 13.0534x over previous
//
#include <hip/hip_runtime.h>
#include <math.h>

#define NROWS 8192
#define DIM   64
#define KSEL  32
#define NQ    (NROWS - KSEL)   /* 8160 query rows */
#define P1LEN 512              /* pass-1 exact prefix */
#define CAP   1024             /* per-query candidate list capacity */
#define FILT_CB 256            /* candidates per filter block */

typedef __attribute__((ext_vector_type(8))) short bf16x8;
typedef __attribute__((ext_vector_type(4))) float f32x4;

// ---------------------------------------------------------------------------
// Kernel A: row norms replicating XLA:CPU (LLVM-vectorized fused reduce):
//   VF=8 lanes, init 0, per-lane FMA chain, horizontal shuffle-tree
//   ((r0+r4)+(r2+r6)) + ((r1+r5)+(r3+r7)).   [validated bit-exact R8-R13]
// ---------------------------------------------------------------------------
__global__ void norms_kernel(const float* __restrict__ x, float* __restrict__ sq) {
    int j = blockIdx.x * blockDim.x + threadIdx.x;
    if (j >= NROWS) return;
    const float* xr = x + (size_t)j * DIM;
    float r[8];
#pragma unroll
    for (int u = 0; u < 8; ++u) r[u] = 0.0f;
#pragma unroll
    for (int i = 0; i < DIM; i += 8) {
#pragma unroll
        for (int u = 0; u < 8; ++u)
            r[u] = __fmaf_rn(xr[i + u], xr[i + u], r[u]);
    }
    const float s04 = __fadd_rn(r[0], r[4]);
    const float s26 = __fadd_rn(r[2], r[6]);
    const float s15 = __fadd_rn(r[1], r[5]);
    const float s37 = __fadd_rn(r[3], r[7]);
    sq[j] = __fadd_rn(__fadd_rn(s04, s26), __fadd_rn(s15, s37));
}

// ---------------------------------------------------------------------------
// Convert x -> bf16 (RNE), 4 elems/thread.
// bf16 RNE rel-err <= 2^-8 per element -> rigorous filter margin (below).
// ---------------------------------------------------------------------------
__global__ __launch_bounds__(256)
void convert_kernel(const float* __restrict__ x, unsigned short* __restrict__ xb) {
    const int i = (blockIdx.x * blockDim.x + threadIdx.x) * 4;
    if (i >= NROWS * DIM) return;
    const float4 v = *reinterpret_cast<const float4*>(x + i);
    const float vv[4] = {v.x, v.y, v.z, v.w};
    unsigned short o[4];
#pragma unroll
    for (int u = 0; u < 4; ++u) {
        const unsigned b = __float_as_uint(vv[u]);
        o[u] = (unsigned short)((b + 0x7FFFu + ((b >> 16) & 1u)) >> 16);
    }
    *reinterpret_cast<ushort4*>(xb + i) = make_ushort4(o[0], o[1], o[2], o[3]);
}

// ---------------------------------------------------------------------------
// Pass 1: ONE WAVE per query.  Exact top-32 over prefix [0, min(512, r)):
// 8 keys/lane in registers, 32 shuffle-only extract-min iterations.
// Writes the 32 keys to lists[qi][0..31], cnt[qi]=32, tau0[qi]=32nd key.
// Distance = bit-exact seq-FMA chain k=0..63 (validated).
// ---------------------------------------------------------------------------
__global__ __launch_bounds__(64)
void pass1_kernel(const float* __restrict__ x, const float* __restrict__ sq,
                  unsigned long long* __restrict__ tau0,
                  unsigned int* __restrict__ cnt,
                  unsigned long long* __restrict__ lists) {
    const int qi   = blockIdx.x;        // 0..8159
    const int r    = qi + KSEL;         // query row (wave-uniform)
    const int lane = threadIdx.x;
    const int P    = min(r, P1LEN);

    const float* qp  = x + (size_t)r * DIM;   // uniform -> scalar loads
    const float  sqr = sq[r];

    unsigned long long key[8];
#pragma unroll
    for (int s = 0; s < 8; ++s) {
        const int j = lane + (s << 6);
        unsigned long long k = ~0ull;
        if (j < P) {
            const float4* c4 = reinterpret_cast<const float4*>(x + (size_t)j * DIM);
            float acc = 0.0f;
#pragma unroll
            for (int i = 0; i < DIM / 4; ++i) {
                float4 v = c4[i];
                acc = __fmaf_rn(qp[4 * i + 0], v.x, acc);
                acc = __fmaf_rn(qp[4 * i + 1], v.y, acc);
                acc = __fmaf_rn(qp[4 * i + 2], v.z, acc);
                acc = __fmaf_rn(qp[4 * i + 3], v.w, acc);
            }
            const float dd =
                fmaxf(__fsub_rn(__fadd_rn(sqr, sq[j]), __fmul_rn(2.0f, acc)), 0.0f);
            k = ((unsigned long long)__float_as_uint(dd) << 32) | (unsigned)j;
        }
        key[s] = k;
    }

    unsigned long long pmin = ~0ull;
#pragma unroll
    for (int s = 0; s < 8; ++s) pmin = key[s] < pmin ? key[s] : pmin;

    unsigned long long g = ~0ull;
    for (int it = 0; it < KSEL; ++it) {
        unsigned long long v = pmin;
#pragma unroll
        for (int off = 32; off > 0; off >>= 1) {
            const unsigned long long o = __shfl_down(v, off, 64);
            v = o < v ? o : v;
        }
        g = __shfl(v, 0, 64);
        if (lane == 0) lists[(size_t)qi * CAP + it] = g;
        if (pmin == g) {            // unique winner (keys embed unique j)
#pragma unroll
            for (int s = 0; s < 8; ++s) if (key[s] == g) key[s] = ~0ull;
            pmin = ~0ull;
#pragma unroll
            for (int s = 0; s < 8; ++s) pmin = key[s] < pmin ? key[s] : pmin;
        }
    }
    if (lane == 0) { tau0[qi] = g; cnt[qi] = KSEL; }
}

// ---------------------------------------------------------------------------
// Filter (v8): bf16 MFMA approximate-distance screen over [512, r).
// R8 POST-MORTEM: the MFMA screen itself is verified correct+cheap (~2us of
// MFMA), but 800K device-scope atomics on ONE paircnt address serialized
// the whole GPU (VALUBusy 0.4%, 5-36ms, huge run variance).  v8 appends
// survivors DIRECTLY into the per-query lists (8160 distinct cnt[] targets,
// ~40 hits each -- the pattern the old pass2 proved is free), aggregated
// per 16-lane slice: one atomic per kg-group per ballot, each to a
// DIFFERENT query.  No global counter, no pairs buffer.
//   * A/B/D fragments and accept rule unchanged from R8 (HW-verified):
//     accept iff d_bf16 <= tau + 2^-6*(sqr+sqc)  [rigorous superset].
//   * Appended entries carry approx bits; refine_kernel rewrites every
//     entry >= 32 with the exact validated fp32 chain (or ~0ull if it
//     fails the exact test), so merge sees exactly the old accepted set.
// ---------------------------------------------------------------------------
__global__ __launch_bounds__(256)
void filter_kernel(const unsigned short* __restrict__ xb,
                   const float* __restrict__ sq,
                   const unsigned long long* __restrict__ tau0,
                   unsigned int* __restrict__ cnt,
                   unsigned long long* __restrict__ lists) {
    const int qb   = blockIdx.x;                        // 64-query tile
    const int jb   = P1LEN + blockIdx.y * FILT_CB;      // candidate tile base
    const int r_hi = min(KSEL + (qb + 1) * 64, NROWS);  // exclusive query cap
    if (jb >= r_hi) return;                             // uniform exit

    const int wave = threadIdx.x >> 6;                  // 0..3
    const int lane = threadIdx.x & 63;
    const int rb   = KSEL + qb * 64 + wave * 16;        // wave's first q row
    const int col  = lane & 15;
    const int kg   = lane >> 4;                         // k-group 0..3

    // A fragments (row rb+col, k = kg*8 + {0..7} and +32): contiguous 16B
    const int arow = min(rb + col, NROWS - 1);
    const bf16x8 a0 = *reinterpret_cast<const bf16x8*>(xb + (size_t)arow * DIM + kg * 8);
    const bf16x8 a1 = *reinterpret_cast<const bf16x8*>(xb + (size_t)arow * DIM + 32 + kg * 8);

    // Epilogue per-lane row data: D rows rb + kg*4 + i
    float sqr[4], thm[4]; int rr[4];
#pragma unroll
    for (int i = 0; i < 4; ++i) {
        const int r = rb + kg * 4 + i;
        rr[i]  = r;
        const int rc = min(r, NROWS - 1);
        sqr[i] = sq[rc];
        thm[i] = (r < NROWS) ? __uint_as_float((unsigned)(tau0[r - KSEL] >> 32))
                             : -1.0f;                   // reject all
    }

    for (int sub = 0; sub < FILT_CB / 16; ++sub) {
        const int j0 = jb + sub * 16;
        if (j0 >= r_hi) break;                          // wave-uniform
        const int j  = j0 + col;
        const int jc = min(j, NROWS - 1);
        const bf16x8 b0 = *reinterpret_cast<const bf16x8*>(xb + (size_t)jc * DIM + kg * 8);
        const bf16x8 b1 = *reinterpret_cast<const bf16x8*>(xb + (size_t)jc * DIM + 32 + kg * 8);
        f32x4 acc = {0.f, 0.f, 0.f, 0.f};
        acc = __builtin_amdgcn_mfma_f32_16x16x32_bf16(a0, b0, acc, 0, 0, 0);
        acc = __builtin_amdgcn_mfma_f32_16x16x32_bf16(a1, b1, acc, 0, 0, 0);
        const float sqc = sq[jc];
#pragma unroll
        for (int i = 0; i < 4; ++i) {
            const float s = __fadd_rn(sqr[i], sqc);
            const float d = __fmaf_rn(-2.0f, acc[i], s);
            const bool accept = (j < rr[i]) && (rr[i] < NROWS) &&
                                (d <= __fmaf_rn(0.015625f, s, thm[i]));
            // per-16-lane-slice aggregation: the 16 cols of a kg-group share
            // ONE query (rr[i]); leader does one atomic to that query's cnt.
            const unsigned long long mask = __ballot(accept);
            const unsigned slice = (unsigned)((mask >> (kg * 16)) & 0xFFFFull);
            if (slice) {
                const int qi = rr[i] - KSEL;            // valid: slice!=0 => accepts
                const int leader = kg * 16 + (int)__builtin_ctz(slice);
                unsigned base = 0;
                if (lane == leader)
                    base = atomicAdd(&cnt[qi], (unsigned)__popc(slice));
                base = __shfl(base, leader, 64);
                if (accept) {
                    const unsigned slot =
                        base + (unsigned)__popc(slice & ((1u << col) - 1u));
                    if (slot < CAP)
                        lists[(size_t)qi * CAP + slot] =
                            ((unsigned long long)__float_as_uint(fmaxf(d, 0.0f)) << 32)
                            | (unsigned)j;
                }
            }
        }
    }
}

// ---------------------------------------------------------------------------
// Refine: ONE WAVE per query.  Entries 0..31 are pass1's exact keys; every
// entry >= 32 came from the bf16 screen.  Recompute the exact VALIDATED
// fp32 chain (k=0..63 ascending, float4 x/y/z/w order) for those entries,
// in place: keep (bits<<32|j) iff bits <= tau_hi, else ~0ull (inert in
// merge, which always has >= 32 real keys).  No atomics.
// ---------------------------------------------------------------------------
__global__ __launch_bounds__(64)
void refine_kernel(const float* __restrict__ x, const float* __restrict__ sq,
                   const unsigned long long* __restrict__ tau0,
                   const unsigned int* __restrict__ cnt,
                   unsigned long long* __restrict__ lists) {
    const int qi   = blockIdx.x;
    const int lane = threadIdx.x;
    const int r    = qi + KSEL;
    const int ne   = min((int)cnt[qi], CAP);
    const unsigned th = (unsigned)(tau0[qi] >> 32);
    const float* qp = x + (size_t)r * DIM;
    const float  sqr = sq[r];
    unsigned long long* dst = lists + (size_t)qi * CAP;

    for (int s = KSEL + lane; s < ne; s += 64) {
        const int j = (int)(unsigned)(dst[s] & 0xFFFFFFFFu);
        const float* cp = x + (size_t)j * DIM;
        float acc = 0.0f;
#pragma unroll
        for (int k = 0; k < DIM; k += 4) {
            const float4 qv = *reinterpret_cast<const float4*>(qp + k);
            const float4 cv = *reinterpret_cast<const float4*>(cp + k);
            acc = __fmaf_rn(qv.x, cv.x, acc);
            acc = __fmaf_rn(qv.y, cv.y, acc);
            acc = __fmaf_rn(qv.z, cv.z, acc);
            acc = __fmaf_rn(qv.w, cv.w, acc);
        }
        const float dd = fmaxf(
            __fsub_rn(__fadd_rn(sqr, sq[j]), __fmul_rn(2.0f, acc)), 0.0f);
        const unsigned bits = __float_as_uint(dd);
        dst[s] = (bits <= th)
                   ? (((unsigned long long)bits << 32) | (unsigned)j)
                   : ~0ull;
    }
}

// ---------------------------------------------------------------------------
// Merge: ONE WAVE per query.  16 keys/lane in registers, 32 shuffle-only
// extract-min iterations.  u64-min = ascending (dist, index), low-index
// ties (validated top_k semantics).  List is a superset of the true top-32.
// ---------------------------------------------------------------------------
__global__ __launch_bounds__(64)
void merge_kernel(const unsigned long long* __restrict__ lists,
                  const unsigned int* __restrict__ cnt,
                  float* __restrict__ out_d, float* __restrict__ out_i) {
    const int qi   = blockIdx.x;     // 0..8159
    const int lane = threadIdx.x;
    const int ne   = min((int)cnt[qi], CAP);
    const unsigned long long* src = lists + (size_t)qi * CAP;

    unsigned long long k[16];
#pragma unroll
    for (int s = 0; s < 16; ++s) {
        const int idx = lane + (s << 6);
        k[s] = (idx < ne) ? src[idx] : ~0ull;
    }
    unsigned long long pmin = ~0ull;
#pragma unroll
    for (int s = 0; s < 16; ++s) pmin = k[s] < pmin ? k[s] : pmin;

    for (int it = 0; it < KSEL; ++it) {
        unsigned long long v = pmin;
#pragma unroll
        for (int off = 32; off > 0; off >>= 1) {
            const unsigned long long o = __shfl_down(v, off, 64);
            v = o < v ? o : v;
        }
        const unsigned long long g = __shfl(v, 0, 64);
        if (lane == 0) {
            out_d[(size_t)qi * KSEL + it] = __uint_as_float((unsigned)(g >> 32));
            out_i[(size_t)qi * KSEL + it] = (float)(unsigned)(g & 0xFFFFFFFFu);
        }
        if (pmin == g) {            // unique winner rescans its registers
#pragma unroll
            for (int s = 0; s < 16; ++s) if (k[s] == g) k[s] = ~0ull;
            pmin = ~0ull;
#pragma unroll
            for (int s = 0; s < 16; ++s) pmin = k[s] < pmin ? k[s] : pmin;
        }
    }
}

extern "C" void kernel_launch(void* const* d_in, const int* in_sizes, int n_in,
                              void* d_out, int out_size, void* d_ws, size_t ws_size,
                              hipStream_t stream) {
    const float* x = (const float*)d_in[0];    // anchor_x [8192, 64] fp32
    float* sq = (float*)d_ws;                                        // 32 KB
    unsigned long long* tau0 =
        (unsigned long long*)((char*)d_ws + 32768);                  // 64 KB
    unsigned int* cnt = (unsigned int*)((char*)d_ws + 98304);        // 32 KB
    unsigned long long* lists =
        (unsigned long long*)((char*)d_ws + 131072);                 // 66.8 MB
    unsigned short* xb =
        (unsigned short*)((char*)d_ws + 66977792);                   // 1 MB bf16
    float* out_d = (float*)d_out;              // [8160, 32] distances
    float* out_i = out_d + (size_t)NQ * KSEL;  // [8160, 32] indices (as fp32)

    norms_kernel<<<NROWS / 256, 256, 0, stream>>>(x, sq);
    pass1_kernel<<<NQ, 64, 0, stream>>>(x, sq, tau0, cnt, lists);
    convert_kernel<<<NROWS * DIM / 1024, 256, 0, stream>>>(x, xb);
    dim3 gf(128, (NROWS - P1LEN) / FILT_CB);   // (query tile, candidate tile)
    filter_kernel<<<gf, 256, 0, stream>>>(xb, sq, tau0, cnt, lists);
    refine_kernel<<<NQ, 64, 0, stream>>>(x, sq, tau0, cnt, lists);
    merge_kernel<<<NQ, 64, 0, stream>>>(lists, cnt, out_d, out_i);
}

// Round 11
// 364.693 us; speedup vs baseline: 15.4097x; 1.1805x over previous
//
#include <hip/hip_runtime.h>
#include <math.h>

#define NROWS 8192
#define DIM   64
#define KSEL  32
#define NQ    (NROWS - KSEL)   /* 8160 query rows */
#define P1LEN 512              /* pass-1 exact prefix */
#define CAP   1024             /* per-query candidate list capacity */
#define FILT_CB 256            /* candidates per filter block */

typedef __attribute__((ext_vector_type(8))) short bf16x8;
typedef __attribute__((ext_vector_type(4))) float f32x4;

// ---------------------------------------------------------------------------
// Kernel A: row norms replicating XLA:CPU (LLVM-vectorized fused reduce):
//   VF=8 lanes, init 0, per-lane FMA chain, horizontal shuffle-tree
//   ((r0+r4)+(r2+r6)) + ((r1+r5)+(r3+r7)).   [validated bit-exact R8-R13]
// ---------------------------------------------------------------------------
__global__ void norms_kernel(const float* __restrict__ x, float* __restrict__ sq) {
    int j = blockIdx.x * blockDim.x + threadIdx.x;
    if (j >= NROWS) return;
    const float* xr = x + (size_t)j * DIM;
    float r[8];
#pragma unroll
    for (int u = 0; u < 8; ++u) r[u] = 0.0f;
#pragma unroll
    for (int i = 0; i < DIM; i += 8) {
#pragma unroll
        for (int u = 0; u < 8; ++u)
            r[u] = __fmaf_rn(xr[i + u], xr[i + u], r[u]);
    }
    const float s04 = __fadd_rn(r[0], r[4]);
    const float s26 = __fadd_rn(r[2], r[6]);
    const float s15 = __fadd_rn(r[1], r[5]);
    const float s37 = __fadd_rn(r[3], r[7]);
    sq[j] = __fadd_rn(__fadd_rn(s04, s26), __fadd_rn(s15, s37));
}

// ---------------------------------------------------------------------------
// Transpose x [8192][64] -> xT [64][8192] via LDS tile (64x64, +1 pad).
// 2 MB total -- a few us.  Enables COALESCED candidate loads in pass1.
// ---------------------------------------------------------------------------
__global__ __launch_bounds__(256)
void transpose_kernel(const float* __restrict__ x, float* __restrict__ xT) {
    __shared__ float tile[64][65];
    const int jb  = blockIdx.x * 64;
    const int t   = threadIdx.x;
    const int row = t >> 2;                 // 0..63
    const int cb  = (t & 3) * 16;           // 0,16,32,48
    const float4* src = reinterpret_cast<const float4*>(
        x + (size_t)(jb + row) * DIM + cb);
#pragma unroll
    for (int i = 0; i < 4; ++i) {
        const float4 v = src[i];
        tile[row][cb + 4 * i + 0] = v.x; tile[row][cb + 4 * i + 1] = v.y;
        tile[row][cb + 4 * i + 2] = v.z; tile[row][cb + 4 * i + 3] = v.w;
    }
    __syncthreads();
    const int k = row;                      // dim index this thread writes
#pragma unroll
    for (int i = 0; i < 4; ++i) {
        float4 w;
        w.x = tile[cb + 4 * i + 0][k]; w.y = tile[cb + 4 * i + 1][k];
        w.z = tile[cb + 4 * i + 2][k]; w.w = tile[cb + 4 * i + 3][k];
        *reinterpret_cast<float4*>(xT + (size_t)k * NROWS + jb + cb + 4 * i) = w;
    }
}

// ---------------------------------------------------------------------------
// Convert x -> bf16 (RNE), 4 elems/thread.
// bf16 RNE rel-err <= 2^-8 per element -> rigorous filter margin (below).
// ---------------------------------------------------------------------------
__global__ __launch_bounds__(256)
void convert_kernel(const float* __restrict__ x, unsigned short* __restrict__ xb) {
    const int i = (blockIdx.x * blockDim.x + threadIdx.x) * 4;
    if (i >= NROWS * DIM) return;
    const float4 v = *reinterpret_cast<const float4*>(x + i);
    const float vv[4] = {v.x, v.y, v.z, v.w};
    unsigned short o[4];
#pragma unroll
    for (int u = 0; u < 4; ++u) {
        const unsigned b = __float_as_uint(vv[u]);
        o[u] = (unsigned short)((b + 0x7FFFu + ((b >> 16) & 1u)) >> 16);
    }
    *reinterpret_cast<ushort4*>(xb + i) = make_ushort4(o[0], o[1], o[2], o[3]);
}

// ---------------------------------------------------------------------------
// Pass 1 (v2): exact top-32 over prefix [0, min(512, r)).
// R9 POST-MORTEM: v1 (64-thr blocks, row-major loads) = 135us @ VALUBusy
// 25%, Occ 45%: lane-strided row reads touched 64 cache lines per load
// (~54us of L1 service per CU) and 64-thr blocks capped residency.
// v2: (a) candidate loads from xT (transposed): lane l owns candidates
// {4l..4l+3, 256+4l..+3}; per k-step 2 coalesced b128 loads (16 lines/wave)
// + 8 FMAs with wave-uniform qp[k] (SGPR operand).  Chain per candidate
// still acc=fma(q_k, c_k, acc), k ascending -- multiply commutation is
// rounding-neutral => BIT-EXACT unchanged.  (b) 256-thr blocks = 4
// independent per-wave queries -> occupancy cap 32 waves/CU.
// Selection (8 keys/lane, 32 shuffle extract-min, u64 keys embed j)
// unchanged -- key set identical, so output order identical.
// ---------------------------------------------------------------------------
__global__ __launch_bounds__(256)
void pass1_kernel(const float* __restrict__ x, const float* __restrict__ xT,
                  const float* __restrict__ sq,
                  unsigned long long* __restrict__ tau0,
                  unsigned int* __restrict__ cnt,
                  unsigned long long* __restrict__ lists) {
    const int wave = threadIdx.x >> 6;  // 0..3: independent query per wave
    const int lane = threadIdx.x & 63;
    const int qi   = blockIdx.x * 4 + wave;   // 0..8159
    const int r    = qi + KSEL;               // query row (wave-uniform)
    const int P    = min(r, P1LEN);

    const float* qp  = x + (size_t)r * DIM;   // uniform -> scalar loads
    const float  sqr = sq[r];

    // ---- distances for 8 candidates/lane, coalesced xT loads
    float acc[8];
#pragma unroll
    for (int u = 0; u < 8; ++u) acc[u] = 0.0f;
    const float4* xT4 = reinterpret_cast<const float4*>(xT);
#pragma unroll 4
    for (int k = 0; k < DIM; ++k) {
        const float  qk = qp[k];
        const float4 c0 = xT4[(size_t)k * (NROWS / 4) + lane];       // j=4l..+3
        const float4 c1 = xT4[(size_t)k * (NROWS / 4) + 64 + lane];  // j=256+4l..+3
        acc[0] = __fmaf_rn(qk, c0.x, acc[0]);
        acc[1] = __fmaf_rn(qk, c0.y, acc[1]);
        acc[2] = __fmaf_rn(qk, c0.z, acc[2]);
        acc[3] = __fmaf_rn(qk, c0.w, acc[3]);
        acc[4] = __fmaf_rn(qk, c1.x, acc[4]);
        acc[5] = __fmaf_rn(qk, c1.y, acc[5]);
        acc[6] = __fmaf_rn(qk, c1.z, acc[6]);
        acc[7] = __fmaf_rn(qk, c1.w, acc[7]);
    }

    unsigned long long key[8];
    {
        const float4 sq0 = *reinterpret_cast<const float4*>(sq + 4 * lane);
        const float4 sq1 = *reinterpret_cast<const float4*>(sq + 256 + 4 * lane);
        const float sqc[8] = {sq0.x, sq0.y, sq0.z, sq0.w,
                              sq1.x, sq1.y, sq1.z, sq1.w};
#pragma unroll
        for (int u = 0; u < 8; ++u) {
            const int j = (u < 4) ? (4 * lane + u) : (256 + 4 * lane + (u - 4));
            const float dd = fmaxf(
                __fsub_rn(__fadd_rn(sqr, sqc[u]), __fmul_rn(2.0f, acc[u])), 0.0f);
            key[u] = (j < P)
                ? (((unsigned long long)__float_as_uint(dd) << 32) | (unsigned)j)
                : ~0ull;
        }
    }

    unsigned long long pmin = ~0ull;
#pragma unroll
    for (int s = 0; s < 8; ++s) pmin = key[s] < pmin ? key[s] : pmin;

    unsigned long long g = ~0ull;
    for (int it = 0; it < KSEL; ++it) {
        unsigned long long v = pmin;
#pragma unroll
        for (int off = 32; off > 0; off >>= 1) {
            const unsigned long long o = __shfl_down(v, off, 64);
            v = o < v ? o : v;
        }
        g = __shfl(v, 0, 64);
        if (lane == 0) lists[(size_t)qi * CAP + it] = g;
        if (pmin == g) {            // unique winner (keys embed unique j)
#pragma unroll
            for (int s = 0; s < 8; ++s) if (key[s] == g) key[s] = ~0ull;
            pmin = ~0ull;
#pragma unroll
            for (int s = 0; s < 8; ++s) pmin = key[s] < pmin ? key[s] : pmin;
        }
    }
    if (lane == 0) { tau0[qi] = g; cnt[qi] = KSEL; }
}

// ---------------------------------------------------------------------------
// Filter (v8, unchanged -- R9-validated): bf16 MFMA screen over [512, r).
// Appends survivors directly into per-query lists (spread atomics, one per
// 16-lane slice).  Accept iff d_bf16 <= tau + 2^-6*(sqr+sqc)  [rigorous
// superset via bf16 RNE err 2^-8/input + Cauchy-Schwarz].
// ---------------------------------------------------------------------------
__global__ __launch_bounds__(256)
void filter_kernel(const unsigned short* __restrict__ xb,
                   const float* __restrict__ sq,
                   const unsigned long long* __restrict__ tau0,
                   unsigned int* __restrict__ cnt,
                   unsigned long long* __restrict__ lists) {
    const int qb   = blockIdx.x;                        // 64-query tile
    const int jb   = P1LEN + blockIdx.y * FILT_CB;      // candidate tile base
    const int r_hi = min(KSEL + (qb + 1) * 64, NROWS);  // exclusive query cap
    if (jb >= r_hi) return;                             // uniform exit

    const int wave = threadIdx.x >> 6;                  // 0..3
    const int lane = threadIdx.x & 63;
    const int rb   = KSEL + qb * 64 + wave * 16;        // wave's first q row
    const int col  = lane & 15;
    const int kg   = lane >> 4;                         // k-group 0..3

    // A fragments (row rb+col, k = kg*8 + {0..7} and +32): contiguous 16B
    const int arow = min(rb + col, NROWS - 1);
    const bf16x8 a0 = *reinterpret_cast<const bf16x8*>(xb + (size_t)arow * DIM + kg * 8);
    const bf16x8 a1 = *reinterpret_cast<const bf16x8*>(xb + (size_t)arow * DIM + 32 + kg * 8);

    // Epilogue per-lane row data: D rows rb + kg*4 + i
    float sqr[4], thm[4]; int rr[4];
#pragma unroll
    for (int i = 0; i < 4; ++i) {
        const int r = rb + kg * 4 + i;
        rr[i]  = r;
        const int rc = min(r, NROWS - 1);
        sqr[i] = sq[rc];
        thm[i] = (r < NROWS) ? __uint_as_float((unsigned)(tau0[r - KSEL] >> 32))
                             : -1.0f;                   // reject all
    }

    for (int sub = 0; sub < FILT_CB / 16; ++sub) {
        const int j0 = jb + sub * 16;
        if (j0 >= r_hi) break;                          // wave-uniform
        const int j  = j0 + col;
        const int jc = min(j, NROWS - 1);
        const bf16x8 b0 = *reinterpret_cast<const bf16x8*>(xb + (size_t)jc * DIM + kg * 8);
        const bf16x8 b1 = *reinterpret_cast<const bf16x8*>(xb + (size_t)jc * DIM + 32 + kg * 8);
        f32x4 acc = {0.f, 0.f, 0.f, 0.f};
        acc = __builtin_amdgcn_mfma_f32_16x16x32_bf16(a0, b0, acc, 0, 0, 0);
        acc = __builtin_amdgcn_mfma_f32_16x16x32_bf16(a1, b1, acc, 0, 0, 0);
        const float sqc = sq[jc];
#pragma unroll
        for (int i = 0; i < 4; ++i) {
            const float s = __fadd_rn(sqr[i], sqc);
            const float d = __fmaf_rn(-2.0f, acc[i], s);
            const bool accept = (j < rr[i]) && (rr[i] < NROWS) &&
                                (d <= __fmaf_rn(0.015625f, s, thm[i]));
            const unsigned long long mask = __ballot(accept);
            const unsigned slice = (unsigned)((mask >> (kg * 16)) & 0xFFFFull);
            if (slice) {
                const int qi = rr[i] - KSEL;            // valid: slice!=0 => accepts
                const int leader = kg * 16 + (int)__builtin_ctz(slice);
                unsigned base = 0;
                if (lane == leader)
                    base = atomicAdd(&cnt[qi], (unsigned)__popc(slice));
                base = __shfl(base, leader, 64);
                if (accept) {
                    const unsigned slot =
                        base + (unsigned)__popc(slice & ((1u << col) - 1u));
                    if (slot < CAP)
                        lists[(size_t)qi * CAP + slot] =
                            ((unsigned long long)__float_as_uint(fmaxf(d, 0.0f)) << 32)
                            | (unsigned)j;
                }
            }
        }
    }
}

// ---------------------------------------------------------------------------
// Refine: ONE WAVE per query.  Entries 0..31 are pass1's exact keys; every
// entry >= 32 came from the bf16 screen.  Recompute the exact VALIDATED
// fp32 chain (k=0..63 ascending, float4 x/y/z/w order) for those entries,
// in place: keep (bits<<32|j) iff bits <= tau_hi, else ~0ull (inert in
// merge, which always has >= 32 real keys).  No atomics.
// ---------------------------------------------------------------------------
__global__ __launch_bounds__(64)
void refine_kernel(const float* __restrict__ x, const float* __restrict__ sq,
                   const unsigned long long* __restrict__ tau0,
                   const unsigned int* __restrict__ cnt,
                   unsigned long long* __restrict__ lists) {
    const int qi   = blockIdx.x;
    const int lane = threadIdx.x;
    const int r    = qi + KSEL;
    const int ne   = min((int)cnt[qi], CAP);
    const unsigned th = (unsigned)(tau0[qi] >> 32);
    const float* qp = x + (size_t)r * DIM;
    const float  sqr = sq[r];
    unsigned long long* dst = lists + (size_t)qi * CAP;

    for (int s = KSEL + lane; s < ne; s += 64) {
        const int j = (int)(unsigned)(dst[s] & 0xFFFFFFFFu);
        const float* cp = x + (size_t)j * DIM;
        float acc = 0.0f;
#pragma unroll
        for (int k = 0; k < DIM; k += 4) {
            const float4 qv = *reinterpret_cast<const float4*>(qp + k);
            const float4 cv = *reinterpret_cast<const float4*>(cp + k);
            acc = __fmaf_rn(qv.x, cv.x, acc);
            acc = __fmaf_rn(qv.y, cv.y, acc);
            acc = __fmaf_rn(qv.z, cv.z, acc);
            acc = __fmaf_rn(qv.w, cv.w, acc);
        }
        const float dd = fmaxf(
            __fsub_rn(__fadd_rn(sqr, sq[j]), __fmul_rn(2.0f, acc)), 0.0f);
        const unsigned bits = __float_as_uint(dd);
        dst[s] = (bits <= th)
                   ? (((unsigned long long)bits << 32) | (unsigned)j)
                   : ~0ull;
    }
}

// ---------------------------------------------------------------------------
// Merge: ONE WAVE per query.  16 keys/lane in registers, 32 shuffle-only
// extract-min iterations.  u64-min = ascending (dist, index), low-index
// ties (validated top_k semantics).  List is a superset of the true top-32.
// ---------------------------------------------------------------------------
__global__ __launch_bounds__(64)
void merge_kernel(const unsigned long long* __restrict__ lists,
                  const unsigned int* __restrict__ cnt,
                  float* __restrict__ out_d, float* __restrict__ out_i) {
    const int qi   = blockIdx.x;     // 0..8159
    const int lane = threadIdx.x;
    const int ne   = min((int)cnt[qi], CAP);
    const unsigned long long* src = lists + (size_t)qi * CAP;

    unsigned long long k[16];
#pragma unroll
    for (int s = 0; s < 16; ++s) {
        const int idx = lane + (s << 6);
        k[s] = (idx < ne) ? src[idx] : ~0ull;
    }
    unsigned long long pmin = ~0ull;
#pragma unroll
    for (int s = 0; s < 16; ++s) pmin = k[s] < pmin ? k[s] : pmin;

    for (int it = 0; it < KSEL; ++it) {
        unsigned long long v = pmin;
#pragma unroll
        for (int off = 32; off > 0; off >>= 1) {
            const unsigned long long o = __shfl_down(v, off, 64);
            v = o < v ? o : v;
        }
        const unsigned long long g = __shfl(v, 0, 64);
        if (lane == 0) {
            out_d[(size_t)qi * KSEL + it] = __uint_as_float((unsigned)(g >> 32));
            out_i[(size_t)qi * KSEL + it] = (float)(unsigned)(g & 0xFFFFFFFFu);
        }
        if (pmin == g) {            // unique winner rescans its registers
#pragma unroll
            for (int s = 0; s < 16; ++s) if (k[s] == g) k[s] = ~0ull;
            pmin = ~0ull;
#pragma unroll
            for (int s = 0; s < 16; ++s) pmin = k[s] < pmin ? k[s] : pmin;
        }
    }
}

extern "C" void kernel_launch(void* const* d_in, const int* in_sizes, int n_in,
                              void* d_out, int out_size, void* d_ws, size_t ws_size,
                              hipStream_t stream) {
    const float* x = (const float*)d_in[0];    // anchor_x [8192, 64] fp32
    float* sq = (float*)d_ws;                                        // 32 KB
    unsigned long long* tau0 =
        (unsigned long long*)((char*)d_ws + 32768);                  // 64 KB
    unsigned int* cnt = (unsigned int*)((char*)d_ws + 98304);        // 32 KB
    unsigned long long* lists =
        (unsigned long long*)((char*)d_ws + 131072);                 // 66.8 MB
    unsigned short* xb =
        (unsigned short*)((char*)d_ws + 66977792);                   // 1 MB bf16
    float* xT = (float*)((char*)d_ws + 68026368);                    // 2 MB fp32
    float* out_d = (float*)d_out;              // [8160, 32] distances
    float* out_i = out_d + (size_t)NQ * KSEL;  // [8160, 32] indices (as fp32)

    norms_kernel<<<NROWS / 256, 256, 0, stream>>>(x, sq);
    transpose_kernel<<<NROWS / 64, 256, 0, stream>>>(x, xT);
    convert_kernel<<<NROWS * DIM / 1024, 256, 0, stream>>>(x, xb);
    pass1_kernel<<<NQ / 4, 256, 0, stream>>>(x, xT, sq, tau0, cnt, lists);
    dim3 gf(128, (NROWS - P1LEN) / FILT_CB);   // (query tile, candidate tile)
    filter_kernel<<<gf, 256, 0, stream>>>(xb, sq, tau0, cnt, lists);
    refine_kernel<<<NQ, 64, 0, stream>>>(x, sq, tau0, cnt, lists);
    merge_kernel<<<NQ, 64, 0, stream>>>(lists, cnt, out_d, out_i);
}